// Round 6
// baseline (71.157 us; speedup 1.0000x reference)
//
#include <hip/hip_runtime.h>
#include <hip/hip_fp16.h>

// Problem constants (match reference)
#define N_NODES 50000
#define E_COUNT 1000000
#define P_COUNT 200000
#define S_COUNT 50
#define EPS_F   1e-6f

constexpr int TPB = 256;
constexpr int EPT = 4;                                   // events per thread
constexpr int EQ  = E_COUNT / EPT;                       // 250000
constexpr int EVENT_BLOCKS = (EQ + TPB - 1) / TPB;       // 977
constexpr int PAIR_BLOCKS  = (P_COUNT + TPB - 1) / TPB;  // 782
constexpr int TOTAL_BLOCKS = PAIR_BLOCKS + EVENT_BLOCKS; // 1759

// Butterfly reduce across the 64-lane wave, then across the 4 waves of a block.
__device__ __forceinline__ float block_reduce_sum(float v) {
    #pragma unroll
    for (int m = 32; m >= 1; m >>= 1) v += __shfl_xor(v, m, 64);
    __shared__ float smem[TPB / 64];
    const int lane = threadIdx.x & 63;
    const int wid  = threadIdx.x >> 6;
    if (lane == 0) smem[wid] = v;
    __syncthreads();
    float r = 0.0f;
    if (threadIdx.x == 0) {
        #pragma unroll
        for (int w = 0; w < TPB / 64; ++w) r += smem[w];
    }
    __syncthreads();
    return r;
}

// One 16B record per node: [zx f32][zy f32][(vx,vy) half2][(ax,ay) half2]
// Also zeroes the completion counter for the fused kernel (runs first each call).
__global__ __launch_bounds__(TPB) void pack_nodes_kernel(
    const float2* __restrict__ z0,
    const float2* __restrict__ v0,
    const float2* __restrict__ a0,
    float4*       __restrict__ packed,
    unsigned*     __restrict__ counter)
{
    const int i = blockIdx.x * TPB + threadIdx.x;
    if (i == 0) *counter = 0u;
    if (i < N_NODES) {
        const float2 z = z0[i], v = v0[i], a = a0[i];
        float4 r;
        r.x = z.x;
        r.y = z.y;
        r.z = __builtin_bit_cast(float, __floats2half2_rn(v.x, v.y));
        r.w = __builtin_bit_cast(float, __floats2half2_rn(a.x, a.y));
        packed[i] = r;
    }
}

__device__ __forceinline__ float event_dist(const float4 pu, const float4 pv,
                                            const float t) {
    const float2 vu = __half22float2(__builtin_bit_cast(__half2, pu.z));
    const float2 vv = __half22float2(__builtin_bit_cast(__half2, pv.z));
    const float2 au = __half22float2(__builtin_bit_cast(__half2, pu.w));
    const float2 av = __half22float2(__builtin_bit_cast(__half2, pv.w));
    const float ht2 = 0.5f * t * t;
    const float fx = (pu.x - pv.x) + (vu.x - vv.x) * t + (au.x - av.x) * ht2 + EPS_F;
    const float fy = (pu.y - pv.y) + (vu.y - vv.y) * t + (au.y - av.y) * ht2 + EPS_F;
    return sqrtf(fx * fx + fy * fy);
}

__global__ __launch_bounds__(TPB) void fused_kernel(
    const float4* __restrict__ packed,
    const float*  __restrict__ events_t,
    const int*    __restrict__ events_uv_flat,   // 2*E ints
    const int*    __restrict__ pairs_u,
    const int*    __restrict__ pairs_v,
    const float*  __restrict__ beta,
    const int*    __restrict__ t0p,
    const int*    __restrict__ tnp,
    float*        __restrict__ partials,
    unsigned*     __restrict__ counter,
    float*        __restrict__ out)
{
    float acc = 0.0f;
    const int b = blockIdx.x;

    if (b < PAIR_BLOCKS) {
        // ---- Non-event term (long exp loop) first for tail overlap.
        const int i = b * TPB + threadIdx.x;
        if (i < P_COUNT) {
            const float t0f = (float)t0p[0];
            const float tnf = (float)tnp[0];
            const float dxs = (tnf - t0f) / (float)S_COUNT;
            const int u = __builtin_nontemporal_load(pairs_u + i);
            const int v = __builtin_nontemporal_load(pairs_v + i);
            const float4 pu = packed[u];
            const float4 pv = packed[v];
            const float2 vu = __half22float2(__builtin_bit_cast(__half2, pu.z));
            const float2 vv = __half22float2(__builtin_bit_cast(__half2, pv.z));
            const float2 au = __half22float2(__builtin_bit_cast(__half2, pu.w));
            const float2 av = __half22float2(__builtin_bit_cast(__half2, pv.w));
            const float dzx = pu.x - pv.x,          dzy = pu.y - pv.y;
            const float dvx = vu.x - vv.x,          dvy = vu.y - vv.y;
            const float dax = 0.5f * (au.x - av.x), day = 0.5f * (au.y - av.y);
            float sacc = 0.0f;
            #pragma unroll 5
            for (int s = 0; s < S_COUNT; ++s) {
                const float tm = t0f + ((float)s + 0.5f) * dxs;
                const float fx = dzx + dvx * tm + dax * tm * tm + EPS_F;
                const float fy = dzy + dvy * tm + day * tm * tm + EPS_F;
                const float dp = sqrtf(fx * fx + fy * fy);
                sacc += __expf(-dp);
            }
            acc = sacc;
        }
    } else {
        // ---- Event term: EPT events/thread; all loads issued up front.
        const int gid = (b - PAIR_BLOCKS) * TPB + threadIdx.x;
        if (gid < EQ) {
            float t[EPT];
            int   iu[EPT], iv[EPT];
            #pragma unroll
            for (int k = 0; k < EPT; ++k) {
                const int e = gid + k * EQ;
                t[k]  = __builtin_nontemporal_load(events_t + e);
                iu[k] = __builtin_nontemporal_load(events_uv_flat + 2 * e);
                iv[k] = __builtin_nontemporal_load(events_uv_flat + 2 * e + 1);
            }
            float4 pu[EPT], pv[EPT];
            #pragma unroll
            for (int k = 0; k < EPT; ++k) {
                pu[k] = packed[iu[k]];
                pv[k] = packed[iv[k]];
            }
            float s = 0.0f;
            #pragma unroll
            for (int k = 0; k < EPT; ++k) s += event_dist(pu[k], pv[k], t[k]);
            acc = s;
        }
    }

    const float r = block_reduce_sum(acc);

    // Publish this block's partial (release, device scope), then count completion.
    __shared__ bool is_last;
    if (threadIdx.x == 0) {
        __hip_atomic_store(&partials[b], r, __ATOMIC_RELEASE, __HIP_MEMORY_SCOPE_AGENT);
        const unsigned old = __hip_atomic_fetch_add(counter, 1u, __ATOMIC_ACQ_REL,
                                                    __HIP_MEMORY_SCOPE_AGENT);
        is_last = (old == (unsigned)(TOTAL_BLOCKS - 1));
    }
    __syncthreads();

    if (is_last) {
        // Fixed-order reduction regardless of which block is last -> deterministic.
        float accP = 0.0f, accE = 0.0f;
        for (int i = threadIdx.x; i < PAIR_BLOCKS; i += TPB)
            accP += __hip_atomic_load(&partials[i], __ATOMIC_ACQUIRE,
                                      __HIP_MEMORY_SCOPE_AGENT);
        for (int i = PAIR_BLOCKS + threadIdx.x; i < TOTAL_BLOCKS; i += TPB)
            accE += __hip_atomic_load(&partials[i], __ATOMIC_ACQUIRE,
                                      __HIP_MEMORY_SCOPE_AGENT);

        const float sumExp = block_reduce_sum(accP);
        const float sumD   = block_reduce_sum(accE);

        if (threadIdx.x == 0) {
            const float bta = beta[0];
            const float t0f = (float)t0p[0];
            const float tnf = (float)tnp[0];
            const float dxs = (tnf - t0f) / (float)S_COUNT;
            const float event_intensity     = (float)E_COUNT * bta - sumD;
            const float non_event_intensity = expf(bta) * sumExp * dxs;
            out[0] = event_intensity - non_event_intensity;  // NON_EVENT_W = 1.0
        }
    }
}

extern "C" void kernel_launch(void* const* d_in, const int* in_sizes, int n_in,
                              void* d_out, int out_size, void* d_ws, size_t ws_size,
                              hipStream_t stream) {
    const float*  beta      = (const float*)d_in[0];
    const float2* z0        = (const float2*)d_in[1];
    const float2* v0        = (const float2*)d_in[2];
    const float2* a0        = (const float2*)d_in[3];
    const float*  events_t  = (const float*)d_in[4];
    const int*    events_uv = (const int*)d_in[5];
    const int*    pairs_u   = (const int*)d_in[6];
    const int*    pairs_v   = (const int*)d_in[7];
    const int*    t0p       = (const int*)d_in[8];
    const int*    tnp       = (const int*)d_in[9];

    // Workspace: [partials: TOTAL_BLOCKS f32][counter @8KB][packed @16KB: N*16B]
    float*    partials = (float*)d_ws;
    unsigned* counter  = (unsigned*)((char*)d_ws + 8192);
    float4*   packed   = (float4*)((char*)d_ws + 16384);
    float*    out      = (float*)d_out;

    pack_nodes_kernel<<<(N_NODES + TPB - 1) / TPB, TPB, 0, stream>>>(
        z0, v0, a0, packed, counter);

    fused_kernel<<<TOTAL_BLOCKS, TPB, 0, stream>>>(
        packed, events_t, events_uv, pairs_u, pairs_v,
        beta, t0p, tnp, partials, counter, out);
}

// Round 7
// 27.003 us; speedup vs baseline: 2.6352x; 2.6352x over previous
//
#include <hip/hip_runtime.h>
#include <hip/hip_fp16.h>

// Problem constants (match reference)
#define N_NODES 50000
#define E_COUNT 1000000
#define P_COUNT 200000
#define S_COUNT 50
#define EPS_F   1e-6f

constexpr int TPB = 256;
constexpr int EPT = 4;                                   // events per thread
constexpr int EQ  = E_COUNT / EPT;                       // 250000
constexpr int EVENT_BLOCKS = (EQ + TPB - 1) / TPB;       // 977
constexpr int PAIR_BLOCKS  = (P_COUNT + TPB - 1) / TPB;  // 782
constexpr int TOTAL_BLOCKS = PAIR_BLOCKS + EVENT_BLOCKS; // 1759

// Butterfly reduce across the 64-lane wave, then across the 4 waves of a block.
__device__ __forceinline__ float block_reduce_sum(float v) {
    #pragma unroll
    for (int m = 32; m >= 1; m >>= 1) v += __shfl_xor(v, m, 64);
    __shared__ float smem[TPB / 64];
    const int lane = threadIdx.x & 63;
    const int wid  = threadIdx.x >> 6;
    if (lane == 0) smem[wid] = v;
    __syncthreads();
    float r = 0.0f;
    if (threadIdx.x == 0) {
        #pragma unroll
        for (int w = 0; w < TPB / 64; ++w) r += smem[w];
    }
    __syncthreads();
    return r;
}

// One 16B record per node: [zx f32][zy f32][(vx,vy) half2][(ax,ay) half2]
__global__ __launch_bounds__(TPB) void pack_nodes_kernel(
    const float2* __restrict__ z0,
    const float2* __restrict__ v0,
    const float2* __restrict__ a0,
    float4*       __restrict__ packed)
{
    const int i = blockIdx.x * TPB + threadIdx.x;
    if (i < N_NODES) {
        const float2 z = z0[i], v = v0[i], a = a0[i];
        float4 r;
        r.x = z.x;
        r.y = z.y;
        r.z = __builtin_bit_cast(float, __floats2half2_rn(v.x, v.y));
        r.w = __builtin_bit_cast(float, __floats2half2_rn(a.x, a.y));
        packed[i] = r;
    }
}

__device__ __forceinline__ float event_dist(const float4 pu, const float4 pv,
                                            const float t) {
    const float2 vu = __half22float2(__builtin_bit_cast(__half2, pu.z));
    const float2 vv = __half22float2(__builtin_bit_cast(__half2, pv.z));
    const float2 au = __half22float2(__builtin_bit_cast(__half2, pu.w));
    const float2 av = __half22float2(__builtin_bit_cast(__half2, pv.w));
    const float ht2 = 0.5f * t * t;
    const float fx = (pu.x - pv.x) + (vu.x - vv.x) * t + (au.x - av.x) * ht2 + EPS_F;
    const float fy = (pu.y - pv.y) + (vu.y - vv.y) * t + (au.y - av.y) * ht2 + EPS_F;
    return sqrtf(fx * fx + fy * fy);
}

__global__ __launch_bounds__(TPB) void fused_partials_kernel(
    const float4* __restrict__ packed,
    const float*  __restrict__ events_t,
    const int*    __restrict__ events_uv_flat,   // 2*E ints
    const int*    __restrict__ pairs_u,
    const int*    __restrict__ pairs_v,
    const int*    __restrict__ t0p,
    const int*    __restrict__ tnp,
    float*        __restrict__ partials)
{
    float acc = 0.0f;
    const int b = blockIdx.x;

    if (b < PAIR_BLOCKS) {
        // ---- Non-event term (long exp loop) first for tail overlap.
        const int i = b * TPB + threadIdx.x;
        if (i < P_COUNT) {
            const float t0f = (float)t0p[0];
            const float tnf = (float)tnp[0];
            const float dxs = (tnf - t0f) / (float)S_COUNT;
            const int u = __builtin_nontemporal_load(pairs_u + i);
            const int v = __builtin_nontemporal_load(pairs_v + i);
            const float4 pu = packed[u];
            const float4 pv = packed[v];
            const float2 vu = __half22float2(__builtin_bit_cast(__half2, pu.z));
            const float2 vv = __half22float2(__builtin_bit_cast(__half2, pv.z));
            const float2 au = __half22float2(__builtin_bit_cast(__half2, pu.w));
            const float2 av = __half22float2(__builtin_bit_cast(__half2, pv.w));
            const float dzx = pu.x - pv.x,          dzy = pu.y - pv.y;
            const float dvx = vu.x - vv.x,          dvy = vu.y - vv.y;
            const float dax = 0.5f * (au.x - av.x), day = 0.5f * (au.y - av.y);
            float sacc = 0.0f;
            #pragma unroll 5
            for (int s = 0; s < S_COUNT; ++s) {
                const float tm = t0f + ((float)s + 0.5f) * dxs;
                const float fx = dzx + dvx * tm + dax * tm * tm + EPS_F;
                const float fy = dzy + dvy * tm + day * tm * tm + EPS_F;
                const float dp = sqrtf(fx * fx + fy * fy);
                sacc += __expf(-dp);
            }
            acc = sacc;
        }
    } else {
        // ---- Event term: EPT events/thread; all loads issued up front.
        const int gid = (b - PAIR_BLOCKS) * TPB + threadIdx.x;
        if (gid < EQ) {
            float t[EPT];
            int   iu[EPT], iv[EPT];
            #pragma unroll
            for (int k = 0; k < EPT; ++k) {
                const int e = gid + k * EQ;
                t[k]  = __builtin_nontemporal_load(events_t + e);
                iu[k] = __builtin_nontemporal_load(events_uv_flat + 2 * e);
                iv[k] = __builtin_nontemporal_load(events_uv_flat + 2 * e + 1);
            }
            float4 pu[EPT], pv[EPT];
            #pragma unroll
            for (int k = 0; k < EPT; ++k) {
                pu[k] = packed[iu[k]];
                pv[k] = packed[iv[k]];
            }
            float s = 0.0f;
            #pragma unroll
            for (int k = 0; k < EPT; ++k) s += event_dist(pu[k], pv[k], t[k]);
            acc = s;
        }
    }

    const float r = block_reduce_sum(acc);
    if (threadIdx.x == 0) partials[b] = r;
}

__global__ __launch_bounds__(TPB) void finalize_kernel(
    const float* __restrict__ partials,
    const float* __restrict__ beta,
    const int*   __restrict__ t0p,
    const int*   __restrict__ tnp,
    float*       __restrict__ out)
{
    float accP = 0.0f, accE = 0.0f;
    for (int i = threadIdx.x; i < PAIR_BLOCKS; i += TPB) accP += partials[i];
    for (int i = PAIR_BLOCKS + threadIdx.x; i < TOTAL_BLOCKS; i += TPB) accE += partials[i];

    const float sumExp = block_reduce_sum(accP);
    const float sumD   = block_reduce_sum(accE);

    if (threadIdx.x == 0) {
        const float bta = beta[0];
        const float t0f = (float)t0p[0];
        const float tnf = (float)tnp[0];
        const float dxs = (tnf - t0f) / (float)S_COUNT;
        const float event_intensity     = (float)E_COUNT * bta - sumD;
        const float non_event_intensity = expf(bta) * sumExp * dxs;
        out[0] = event_intensity - non_event_intensity;  // NON_EVENT_W = 1.0
    }
}

extern "C" void kernel_launch(void* const* d_in, const int* in_sizes, int n_in,
                              void* d_out, int out_size, void* d_ws, size_t ws_size,
                              hipStream_t stream) {
    const float*  beta      = (const float*)d_in[0];
    const float2* z0        = (const float2*)d_in[1];
    const float2* v0        = (const float2*)d_in[2];
    const float2* a0        = (const float2*)d_in[3];
    const float*  events_t  = (const float*)d_in[4];
    const int*    events_uv = (const int*)d_in[5];
    const int*    pairs_u   = (const int*)d_in[6];
    const int*    pairs_v   = (const int*)d_in[7];
    const int*    t0p       = (const int*)d_in[8];
    const int*    tnp       = (const int*)d_in[9];

    // Workspace layout: [partials: TOTAL_BLOCKS floats][pad to 16KB][packed: N*16B]
    const size_t packed_off = 16384;
    float* partials = (float*)d_ws;
    float4* packed  = (float4*)((char*)d_ws + packed_off);
    float* out      = (float*)d_out;

    pack_nodes_kernel<<<(N_NODES + TPB - 1) / TPB, TPB, 0, stream>>>(z0, v0, a0, packed);

    fused_partials_kernel<<<TOTAL_BLOCKS, TPB, 0, stream>>>(
        packed, events_t, events_uv, pairs_u, pairs_v, t0p, tnp, partials);

    finalize_kernel<<<1, TPB, 0, stream>>>(partials, beta, t0p, tnp, out);
}